// Round 4
// baseline (381.073 us; speedup 1.0000x reference)
//
#include <hip/hip_runtime.h>
#include <stdint.h>

typedef unsigned short u16;
typedef __bf16 bf16x8 __attribute__((ext_vector_type(8)));
typedef float floatx4 __attribute__((ext_vector_type(4)));

#define AS1(p) ((__attribute__((address_space(1))) void*)(void*)(p))
#define AS3(p) ((__attribute__((address_space(3))) void*)(p))

__device__ __forceinline__ u16 f2bf(float f) {
    unsigned u;
    __builtin_memcpy(&u, &f, 4);
    u += 0x7FFF + ((u >> 16) & 1);   // RNE
    return (u16)(u >> 16);
}
__device__ __forceinline__ u16 f2bf_trunc(float f) {
    unsigned u;
    __builtin_memcpy(&u, &f, 4);
    return (u16)(u >> 16);
}
__device__ __forceinline__ float exp2_fast(float x) {
    return __builtin_amdgcn_exp2f(x);    // v_exp_f32
}
__device__ __forceinline__ float gelu_f(float x) {
    return 0.5f * x * (1.0f + erff(x * 0.70710678118654752f));
}

// ---------------------------------------------------------------------------
// Convert the 6 weight matrices fp32 -> bf16 into ws (layout: wq wk wv wo f1 f2)
// ---------------------------------------------------------------------------
__global__ __launch_bounds__(256) void conv_w_kernel(
    const float* __restrict__ wq, const float* __restrict__ wk,
    const float* __restrict__ wv, const float* __restrict__ wo,
    const float* __restrict__ f1, const float* __restrict__ f2,
    const float* __restrict__ bq, const float* __restrict__ bk,
    const float* __restrict__ bv, float* __restrict__ qkvb,
    u16* __restrict__ W) {
    const size_t i4 = ((size_t)blockIdx.x * 256 + threadIdx.x) * 4;
    const size_t M1 = 1048576;
    const float* src;
    size_t off;
    if (i4 < M1)            { src = wq; off = i4; }
    else if (i4 < 2 * M1)   { src = wk; off = i4 - M1; }
    else if (i4 < 3 * M1)   { src = wv; off = i4 - 2 * M1; }
    else if (i4 < 4 * M1)   { src = wo; off = i4 - 3 * M1; }
    else if (i4 < 8 * M1)   { src = f1; off = i4 - 4 * M1; }
    else                    { src = f2; off = i4 - 8 * M1; }
    float4 d = *(const float4*)(src + off);
    ushort4 o;
    o.x = f2bf(d.x); o.y = f2bf(d.y); o.z = f2bf(d.z); o.w = f2bf(d.w);
    *(ushort4*)(W + i4) = o;
    if (blockIdx.x == 0) {
        for (int i = threadIdx.x; i < 1024; i += 256) {
            qkvb[i] = bq[i];
            qkvb[1024 + i] = bk[i];
            qkvb[2048 + i] = bv[i];
        }
    }
}

// ---------------------------------------------------------------------------
// LayerNorm: one wave per token row (D=1024 -> 16 elems/lane). fp32 in, bf16 out.
// ---------------------------------------------------------------------------
__global__ __launch_bounds__(64) void ln_kernel(const float* __restrict__ X,
                                                const float* __restrict__ G,
                                                const float* __restrict__ Bt,
                                                u16* __restrict__ Y) {
    const int row = blockIdx.x;
    const int lane = threadIdx.x;
    const float* xr = X + (size_t)row * 1024;
    float v[16];
    float s = 0.f;
#pragma unroll
    for (int i = 0; i < 16; ++i) { v[i] = xr[lane + i * 64]; s += v[i]; }
#pragma unroll
    for (int off = 1; off < 64; off <<= 1) s += __shfl_xor(s, off, 64);
    const float mu = s * (1.0f / 1024.0f);
    float ss = 0.f;
#pragma unroll
    for (int i = 0; i < 16; ++i) { float d = v[i] - mu; ss += d * d; }
#pragma unroll
    for (int off = 1; off < 64; off <<= 1) ss += __shfl_xor(ss, off, 64);
    const float rstd = rsqrtf(ss * (1.0f / 1024.0f) + 1e-5f);
    u16* yr = Y + (size_t)row * 1024;
#pragma unroll
    for (int i = 0; i < 16; ++i) {
        int c = lane + i * 64;
        yr[c] = f2bf((v[i] - mu) * rstd * G[c] + Bt[c]);
    }
}

// ---------------------------------------------------------------------------
// gemm128sq: 128x128 tile, 4 waves (2Mx2N, 64x64 each), BK=64,
// 4-buffer LDS pipeline staged 3 tiles ahead (counted vmcnt 16/8/0 tail),
// T2 XOR-swizzle via inverse-swizzled global source + linear global_load_lds
// dest + swizzled ds_read (rule #21), setprio around the 32-MFMA cluster.
// fp32 out = A@Bt^T + bias + resid. Grid (M/128, N/128). 128 KiB dyn LDS.
// Per-iteration order (tile T):
//   vmcnt(16|8|0)  [retire tile T's 8 loads, issued at T-3]
//   s_barrier      [all waves waited -> ALL of tile T's staging visible]
//   stage(T+3)     [buf (T+3)%4 = (T-1)%4; its readers retired by this barrier]
//   ds_read frags(buf T%4); lgkmcnt(0); 32 MFMA
// ---------------------------------------------------------------------------
__global__ __launch_bounds__(256, 1) void gemm128sq_kernel(
    const u16* __restrict__ A, const u16* __restrict__ Bt,
    const float* __restrict__ bias, const float* __restrict__ resid,
    float* __restrict__ C, int M, int N, int K) {
    extern __shared__ __align__(16) u16 smem[];   // 4 bufs x (A 8192 + B 8192) u16
    const int tid = threadIdx.x;
    const int wave = tid >> 6, lane = tid & 63;
    const int wm = (wave >> 1) * 64;
    const int wn = (wave & 1) * 64;
    const int lr = lane & 15, lk8 = (lane >> 4) * 8;
    const int r0 = (lane >> 4) * 4;
    const int m0 = blockIdx.x * 128, n0 = blockIdx.y * 128;
    const int NT = K >> 6;                        // 16 or 64
    const u16* const Ab = A + (size_t)m0 * K;
    const u16* const Bb = Bt + (size_t)n0 * K;

    // staging: linear LDS dest (chunk l: rows 32l..32l+31; thread's 16B at tid*16B),
    // inverse-swizzled global source column.
    const int srow = tid >> 3;                    // 0..31
    const int scol = 8 * ((tid & 7) ^ (srow & 7));
    const int sdst = tid * 8;                     // u16 offset within 2048-u16 chunk
    // read-side swizzle: elem col c at LDS row R -> c ^ ((R&7)<<3); R&7 == lr&7
    const int swz = (lr & 7) << 3;
    const int c0 = lk8 ^ swz;
    const int c1 = (32 + lk8) ^ swz;

    floatx4 acc[4][4];
#pragma unroll
    for (int i = 0; i < 4; ++i)
#pragma unroll
        for (int j = 0; j < 4; ++j) acc[i][j] = floatx4{0.f, 0.f, 0.f, 0.f};
    bf16x8 aF[4][2], bF[4][2];

#define STG(Tt)                                                                \
    {                                                                          \
        u16* const buf = smem + ((Tt) & 3) * 16384;                            \
        _Pragma("unroll")                                                      \
        for (int l = 0; l < 4; ++l) {                                          \
            const u16* srcA = Ab + (size_t)(l * 32 + srow) * K +               \
                              (size_t)(Tt) * 64 + scol;                        \
            __builtin_amdgcn_global_load_lds(                                  \
                AS1(srcA), AS3(buf + l * 2048 + sdst), 16, 0, 0);              \
        }                                                                      \
        _Pragma("unroll")                                                      \
        for (int l = 0; l < 4; ++l) {                                          \
            const u16* srcB = Bb + (size_t)(l * 32 + srow) * K +               \
                              (size_t)(Tt) * 64 + scol;                        \
            __builtin_amdgcn_global_load_lds(                                  \
                AS1(srcB), AS3(buf + 8192 + l * 2048 + sdst), 16, 0, 0);       \
        }                                                                      \
    }

    STG(0); STG(1); STG(2);
    for (int T = 0; T < NT; ++T) {
        const int rem = NT - 1 - T;
        if (rem >= 2)      asm volatile("s_waitcnt vmcnt(16)" ::: "memory");
        else if (rem == 1) asm volatile("s_waitcnt vmcnt(8)" ::: "memory");
        else               asm volatile("s_waitcnt vmcnt(0)" ::: "memory");
        asm volatile("s_barrier" ::: "memory");
        if (T + 3 < NT) STG(T + 3);
        const u16* const bufA = smem + (T & 3) * 16384;
        const u16* const bufB = bufA + 8192;
#pragma unroll
        for (int i = 0; i < 4; ++i) {
            aF[i][0] = *(const bf16x8*)&bufA[(wm + i * 16 + lr) * 64 + c0];
            aF[i][1] = *(const bf16x8*)&bufA[(wm + i * 16 + lr) * 64 + c1];
        }
#pragma unroll
        for (int j = 0; j < 4; ++j) {
            bF[j][0] = *(const bf16x8*)&bufB[(wn + j * 16 + lr) * 64 + c0];
            bF[j][1] = *(const bf16x8*)&bufB[(wn + j * 16 + lr) * 64 + c1];
        }
        asm volatile("s_waitcnt lgkmcnt(0)" ::: "memory");
        __builtin_amdgcn_sched_barrier(0);
        __builtin_amdgcn_s_setprio(1);
#pragma unroll
        for (int i = 0; i < 4; ++i)
#pragma unroll
            for (int j = 0; j < 4; ++j)
#pragma unroll
                for (int kk = 0; kk < 2; ++kk)
                    acc[i][j] = __builtin_amdgcn_mfma_f32_16x16x32_bf16(
                        aF[i][kk], bF[j][kk], acc[i][j], 0, 0, 0);
        __builtin_amdgcn_s_setprio(0);
    }
#undef STG

    // epilogue: fp32 out = acc + bias + resid
#pragma unroll
    for (int i = 0; i < 4; ++i)
#pragma unroll
        for (int j = 0; j < 4; ++j) {
            const int col = n0 + wn + j * 16 + lr;
            const float bv = bias[col];
#pragma unroll
            for (int r = 0; r < 4; ++r) {
                const int row = m0 + wm + i * 16 + r0 + r;
                C[(size_t)row * N + col] =
                    acc[i][j][r] + bv + resid[(size_t)row * N + col];
            }
        }
}

// ---------------------------------------------------------------------------
// gemm256: 256x256 tile, BK=64, 8 waves (2Mx4N), phase-interleaved pipeline.
// T1 + T2 + T3/T4 + T5 (see round-1 notes).
// ---------------------------------------------------------------------------
__global__ __launch_bounds__(512, 2) void gemm256_kernel(
    const u16* __restrict__ A, const u16* __restrict__ Bt,
    const float* __restrict__ bias, u16* __restrict__ C,
    int M, int N, int K, int act) {
    extern __shared__ __align__(16) u16 smem[];
    u16* const lA = smem;          // [2][256*64] = 64 KiB
    u16* const lB = smem + 32768;  // [2][256*64] = 64 KiB
    const int tid = threadIdx.x;
    const int wave = tid >> 6, lane = tid & 63;
    const int wm = (wave >> 2) * 128;        // wave M-origin (0/128)
    const int wn = (wave & 3) * 64;          // wave N-origin (0/64/128/192)
    const int lr = lane & 15, lk8 = (lane >> 4) * 8;
    const int r0 = (lane >> 4) * 4;

    const int gM = M >> 8;
    int bid = blockIdx.x;
    { const int nwg = gridDim.x;
      const int q = nwg >> 3, r = nwg & 7, xcd = bid & 7, lid = bid >> 3;
      bid = (xcd < r ? xcd * (q + 1) : r * (q + 1) + (xcd - r) * q) + lid; }
    const int m0 = (bid % gM) << 8;
    const int n0 = (bid / gM) << 8;

    const int NT = K >> 6;                   // 64-wide K tiles (even, >=16 here)
    const u16* const Ab = A + (size_t)m0 * K;
    const u16* const Bb = Bt + (size_t)n0 * K;

    const int srow = tid >> 3;                         // 0..63
    const int scol = 8 * ((tid & 7) ^ (srow & 7));     // element col, inv-swizzled
    const int sdst = tid * 8;                          // u16 offset (lane*16 B)
    const int swz = (lr & 7) << 3;
    const int c0 = lk8 ^ swz;                          // kk=0 frag col
    const int c1 = (32 + lk8) ^ swz;                   // kk=1 frag col

    floatx4 acc[8][4];
#pragma unroll
    for (int i = 0; i < 8; ++i)
#pragma unroll
        for (int j = 0; j < 4; ++j) acc[i][j] = floatx4{0.f, 0.f, 0.f, 0.f};
    bf16x8 aF[2][4][2];   // [mq][i][kk]
    bf16x8 bF[4][2];      // [nf][kk]

#define STAGE_HT(ldsbuf, gbase, h, Tt)                                         \
    {                                                                          \
        _Pragma("unroll")                                                      \
        for (int l = 0; l < 2; ++l) {                                          \
            const u16* src = (gbase) + (size_t)((h) * 128 + l * 64 + srow) * K \
                             + (size_t)(Tt) * 64 + scol;                       \
            __builtin_amdgcn_global_load_lds(                                  \
                AS1(src), AS3((ldsbuf) + (h) * 8192 + l * 4096 + sdst), 16, 0, 0); \
        }                                                                      \
    }
#define PH_BAR() asm volatile("s_barrier" ::: "memory")
#define LGKM0()                                                                \
    do { asm volatile("s_waitcnt lgkmcnt(0)" ::: "memory");                    \
         __builtin_amdgcn_sched_barrier(0); } while (0)
#define MFMA_Q(mq, nq)                                                         \
    __builtin_amdgcn_s_setprio(1);                                             \
    _Pragma("unroll")                                                          \
    for (int i = 0; i < 4; ++i)                                                \
        _Pragma("unroll")                                                      \
        for (int j = 0; j < 2; ++j)                                            \
            _Pragma("unroll")                                                  \
            for (int kk = 0; kk < 2; ++kk)                                     \
                acc[(mq) * 4 + i][(nq) * 2 + j] =                              \
                    __builtin_amdgcn_mfma_f32_16x16x32_bf16(                   \
                        aF[mq][i][kk], bF[(nq) * 2 + j][kk],                   \
                        acc[(mq) * 4 + i][(nq) * 2 + j], 0, 0, 0);             \
    __builtin_amdgcn_s_setprio(0);

#define GROUP(P, T)                                                            \
    {                                                                          \
        u16* const lAp = lA + (P) * 16384;                                     \
        u16* const lBp = lB + (P) * 16384;                                     \
        u16* const lBn = lB + ((P) ^ 1) * 16384;                               \
        /* phase 1 */                                                          \
        _Pragma("unroll")                                                      \
        for (int i = 0; i < 4; ++i) {                                          \
            aF[0][i][0] = *(const bf16x8*)&lAp[(wm + i * 16 + lr) * 64 + c0];  \
            aF[0][i][1] = *(const bf16x8*)&lAp[(wm + i * 16 + lr) * 64 + c1];  \
        }                                                                      \
        _Pragma("unroll")                                                      \
        for (int nf = 0; nf < 4; ++nf) {                                       \
            bF[nf][0] = *(const bf16x8*)&lBp[(wn + nf * 16 + lr) * 64 + c0];   \
            bF[nf][1] = *(const bf16x8*)&lBp[(wn + nf * 16 + lr) * 64 + c1];   \
        }                                                                      \
        if ((T) + 1 < NT) STAGE_HT(lBn, Bb, 0, (T) + 1);                       \
        PH_BAR(); LGKM0();                                                     \
        MFMA_Q(0, 0);                                                          \
        PH_BAR();                                                              \
        /* phase 2 */                                                          \
        _Pragma("unroll")                                                      \
        for (int i = 0; i < 4; ++i) {                                          \
            aF[1][i][0] = *(const bf16x8*)&lAp[(wm + 64 + i * 16 + lr) * 64 + c0]; \
            aF[1][i][1] = *(const bf16x8*)&lAp[(wm + 64 + i * 16 + lr) * 64 + c1]; \
        }                                                                      \
        if ((T) + 1 < NT) STAGE_HT(lBn, Bb, 1, (T) + 1);                       \
        PH_BAR(); LGKM0();                                                     \
        MFMA_Q(0, 1);                                                          \
        PH_BAR();                                                              \
        /* phase 3: A reads of buf P all retired by the ph2-end barrier */     \
        if ((T) + 2 < NT) STAGE_HT(lAp, Ab, 0, (T) + 2);                       \
        MFMA_Q(1, 0);                                                          \
        /* phase 4 */                                                          \
        if ((T) + 2 < NT) STAGE_HT(lAp, Ab, 1, (T) + 2);                       \
        MFMA_Q(1, 1);                                                          \
        if ((T) + 2 < NT) asm volatile("s_waitcnt vmcnt(4)" ::: "memory");     \
        else              asm volatile("s_waitcnt vmcnt(0)" ::: "memory");     \
        PH_BAR();                                                              \
    }

    // prologue: T0 fully + T1 A-halves issued; wait oldest 8 (= all of T0)
    STAGE_HT(lA, Ab, 0, 0);
    STAGE_HT(lA, Ab, 1, 0);
    STAGE_HT(lB, Bb, 0, 0);
    STAGE_HT(lB, Bb, 1, 0);
    if (NT > 1) {
        STAGE_HT(lA + 16384, Ab, 0, 1);
        STAGE_HT(lA + 16384, Ab, 1, 1);
    }
    asm volatile("s_waitcnt vmcnt(4)" ::: "memory");
    PH_BAR();

    for (int T = 0; T < NT; T += 2) {
        GROUP(0, T);
        GROUP(1, T + 1);
    }
#undef GROUP
#undef MFMA_Q
#undef LGKM0
#undef PH_BAR
#undef STAGE_HT

    // epilogue: bias (+gelu) -> bf16
#pragma unroll
    for (int mq = 0; mq < 2; ++mq)
#pragma unroll
        for (int i = 0; i < 4; ++i)
#pragma unroll
            for (int nf = 0; nf < 4; ++nf) {
                const int col = n0 + wn + nf * 16 + lr;
                const float bv = bias[col];
                floatx4 v = acc[mq * 4 + i][nf];
#pragma unroll
                for (int r = 0; r < 4; ++r) {
                    const int row = m0 + wm + mq * 64 + i * 16 + r0 + r;
                    float x = v[r] + bv;
                    if (act) x = gelu_f(x);
                    C[(size_t)row * N + col] = f2bf(x);
                }
            }
}

// ---------------------------------------------------------------------------
// Transpose the V columns of qkv [4096][3072] into vT [32*64][2048]
// ---------------------------------------------------------------------------
__global__ __launch_bounds__(256) void transp_v(const u16* __restrict__ qkv,
                                                u16* __restrict__ vT) {
    __shared__ u16 lT[64 * 64];
    const int bh = blockIdx.x, tt = blockIdx.y;
    const int b = bh >> 4, h = bh & 15;
    const int t0 = tt * 64;
    const int tid = threadIdx.x;
    const int srow = tid >> 3, scol = (tid & 7) * 8;
#pragma unroll
    for (int rr = 0; rr < 2; ++rr) {
        const int row = srow + rr * 32;  // t-local
        uint4 d4 = *(const uint4*)(qkv + (size_t)(b * 2048 + t0 + row) * 3072 +
                                   2048 + h * 64 + scol);
        const u16* e = (const u16*)&d4;
#pragma unroll
        for (int t = 0; t < 8; ++t) lT[(scol + t) * 64 + row] = e[t];
    }
    __syncthreads();
#pragma unroll
    for (int rr = 0; rr < 2; ++rr) {
        const int row = srow + rr * 32;  // d index
        uint4 d4 = *(const uint4*)&lT[row * 64 + scol];
        *(uint4*)(vT + (size_t)(bh * 64 + row) * 2048 + t0 + scol) = d4;
    }
}

// ---------------------------------------------------------------------------
// Causal flash attention v6: merged pair + max-free softmax + T2 XOR-swizzle
// on all K/V/P LDS paths (rule #21 for the global_load_lds-staged K/V) +
// double-buffered K/V with counted vmcnt(4) + setprio around MFMA clusters.
// ---------------------------------------------------------------------------
__global__ __launch_bounds__(256) void attn_kernel(const u16* __restrict__ qkv,
                                                   const u16* __restrict__ vT,
                                                   u16* __restrict__ O) {
    __shared__ __align__(16) u16 lK[2][64 * 64];     // [buf][key][dh]  16 KiB
    __shared__ __align__(16) u16 lV[2][64 * 64];     // [buf][dh][key]  16 KiB
    __shared__ __align__(16) u16 lP[4][16 * 64];     // per-wave P       8 KiB
    const int tid = threadIdx.x;
    const int wave = tid >> 6, lane = tid & 63;
    const int lr = lane & 15, khi = lane >> 4, lk8 = khi * 8;
    const int p = blockIdx.x;                        // 0..15; qa=31-p first
    const int bh = blockIdx.y;
    const int b = bh >> 4, hh = bh & 15;
    const int rb = b * 2048;
    const size_t vbase = (size_t)(bh * 64) * 2048;
    const int r0 = khi * 4;
    const int qa = 31 - p, qb = p;
    const int qa0 = qa * 64, qb0 = qb * 64;
    const float C = 0.125f * 1.44269504088896f;      // scale * log2(e)

    // staging: linear LDS dest (rr*2048 + tid*8 u16), inverse-swizzled global col
    const int srow = tid >> 3;                       // 0..31
    const int scol = 8 * ((tid & 7) ^ (srow & 7));   // swizzled col within 64
    const int sdst = tid * 8;
    // read-side swizzle: col c at LDS row -> c ^ ((row&7)<<3); row&7 == lr&7
    const int swz = (lr & 7) << 3;
    const int cc0 = lk8 ^ swz;
    const int cc1 = (32 + lk8) ^ swz;

    // Q A-fragments for both tiles (direct from global; no LDS)
    bf16x8 aqA0, aqA1, aqB0, aqB1;
    {
        const size_t qoffA = (size_t)(rb + qa0 + wave * 16 + lr) * 3072 + hh * 64;
        aqA0 = *(const bf16x8*)(qkv + qoffA + lk8);
        aqA1 = *(const bf16x8*)(qkv + qoffA + 32 + lk8);
        const size_t qoffB = (size_t)(rb + qb0 + wave * 16 + lr) * 3072 + hh * 64;
        aqB0 = *(const bf16x8*)(qkv + qoffB + lk8);
        aqB1 = *(const bf16x8*)(qkv + qoffB + 32 + lk8);
    }

    floatx4 oA[4], oB[4];
    float lA_[4], lB_[4];                            // per-lane partial sums
#pragma unroll
    for (int r = 0; r < 4; ++r) {
        oA[r] = floatx4{0.f, 0.f, 0.f, 0.f};
        oB[r] = floatx4{0.f, 0.f, 0.f, 0.f};
        lA_[r] = 0.f; lB_[r] = 0.f;
    }

#define ASTAGE(Pb, kt_)                                                        \
    {                                                                          \
        const int k0_ = (kt_) * 64;                                            \
        _Pragma("unroll")                                                      \
        for (int rr = 0; rr < 2; ++rr) {                                       \
            const int row = srow + rr * 32;                                    \
            __builtin_amdgcn_global_load_lds(                                  \
                AS1(qkv + (size_t)(rb + k0_ + row) * 3072 + 1024 + hh * 64 + scol), \
                AS3(lK[Pb] + rr * 2048 + sdst), 16, 0, 0);                     \
            __builtin_amdgcn_global_load_lds(                                  \
                AS1(vT + vbase + (size_t)row * 2048 + k0_ + scol),             \
                AS3(lV[Pb] + rr * 2048 + sdst), 16, 0, 0);                     \
        }                                                                      \
    }

    // One QK->exp->PV round for one tile against the staged k-tile (buf Pb).
#define TILE_ROUND(Pb, aq0_, aq1_, oo_, ll_, q0_, diag_, k0_)                   \
    {                                                                           \
        float s[4][4];                                                          \
        __builtin_amdgcn_s_setprio(1);                                          \
        _Pragma("unroll")                                                       \
        for (int j = 0; j < 4; ++j) {                                           \
            bf16x8 bk0 = *(const bf16x8*)&lK[Pb][(j * 16 + lr) * 64 + cc0];     \
            bf16x8 bk1 = *(const bf16x8*)&lK[Pb][(j * 16 + lr) * 64 + cc1];     \
            floatx4 t = floatx4{0.f, 0.f, 0.f, 0.f};                            \
            t = __builtin_amdgcn_mfma_f32_16x16x32_bf16(aq0_, bk0, t, 0, 0, 0); \
            t = __builtin_amdgcn_mfma_f32_16x16x32_bf16(aq1_, bk1, t, 0, 0, 0); \
            _Pragma("unroll")                                                   \
            for (int r = 0; r < 4; ++r) s[j][r] = t[r];                         \
        }                                                                       \
        __builtin_amdgcn_s_setprio(0);                                          \
        if (diag_) {                                                            \
            _Pragma("unroll")                                                   \
            for (int j = 0; j < 4; ++j)                                         \
                _Pragma("unroll")                                               \
                for (int r = 0; r < 4; ++r)                                     \
                    if ((k0_) + j * 16 + lr > (q0_) + wave * 16 + r0 + r)       \
                        s[j][r] = -1e30f;                                       \
        }                                                                       \
        _Pragma("unroll")                                                       \
        for (int j = 0; j < 4; ++j)                                             \
            _Pragma("unroll")                                                   \
            for (int r = 0; r < 4; ++r) {                                       \
                float pv = exp2_fast(s[j][r] * C);                              \
                ll_[r] += pv;                                                   \
                lP[wave][(r0 + r) * 64 +                                        \
                         ((j * 16 + lr) ^ (((r0 + r) & 7) << 3))] =             \
                    f2bf_trunc(pv);                                             \
            }                                                                   \
        bf16x8 ap0 = *(const bf16x8*)&lP[wave][lr * 64 + cc0];                  \
        bf16x8 ap1 = *(const bf16x8*)&lP[wave][lr * 64 + cc1];                  \
        __builtin_amdgcn_s_setprio(1);                                          \
        _Pragma("unroll")                                                       \
        for (int jd = 0; jd < 4; ++jd) {                                        \
            bf16x8 bv0 = *(const bf16x8*)&lV[Pb][(jd * 16 + lr) * 64 + cc0];    \
            bf16x8 bv1 = *(const bf16x8*)&lV[Pb][(jd * 16 + lr) * 64 + cc1];    \
            oo_[jd] = __builtin_amdgcn_mfma_f32_16x16x32_bf16(ap0, bv0, oo_[jd], 0, 0, 0); \
            oo_[jd] = __builtin_amdgcn_mfma_f32_16x16x32_bf16(ap1, bv1, oo_[jd], 0, 0, 0); \
        }                                                                       \
        __builtin_amdgcn_s_setprio(0);                                          \
    }

    ASTAGE(0, 0);
    for (int kt = 0; kt <= qa; ++kt) {
        const int P = kt & 1;
        const int k0 = kt * 64;
        if (kt < qa) {
            ASTAGE(P ^ 1, kt + 1);
            asm volatile("s_waitcnt vmcnt(4)" ::: "memory");
        } else {
            asm volatile("s_waitcnt vmcnt(0)" ::: "memory");
        }
        asm volatile("s_barrier" ::: "memory");

        TILE_ROUND(P, aqA0, aqA1, oA, lA_, qa0, kt == qa, k0);
        if (kt <= qb)
            TILE_ROUND(P, aqB0, aqB1, oB, lB_, qb0, kt == qb, k0);

        asm volatile("s_barrier" ::: "memory");  // retire buf-P reads before restage
    }
#undef TILE_ROUND
#undef ASTAGE

    // one-time denominator reduce over the 16 lanes sharing khi (lr bits)
#pragma unroll
    for (int off = 1; off < 16; off <<= 1)
#pragma unroll
        for (int r = 0; r < 4; ++r) {
            lA_[r] += __shfl_xor(lA_[r], off, 64);
            lB_[r] += __shfl_xor(lB_[r], off, 64);
        }

    // normalize + store ctx for both tiles (lane's rows are khi*4+r)
#pragma unroll
    for (int r = 0; r < 4; ++r) {
        const float invA = 1.0f / lA_[r];
        const float invB = 1.0f / lB_[r];
#pragma unroll
        for (int jd = 0; jd < 4; ++jd) {
            const size_t offA = (size_t)(rb + qa0 + wave * 16 + r0 + r) * 1024 +
                                hh * 64 + jd * 16 + lr;
            O[offA] = f2bf(oA[jd][r] * invA);
            const size_t offB = (size_t)(rb + qb0 + wave * 16 + r0 + r) * 1024 +
                                hh * 64 + jd * 16 + lr;
            O[offB] = f2bf(oB[jd][r] * invB);
        }
    }
}

// ---------------------------------------------------------------------------
extern "C" void kernel_launch(void* const* d_in, const int* in_sizes, int n_in,
                              void* d_out, int out_size, void* d_ws, size_t ws_size,
                              hipStream_t stream) {
    const float* x     = (const float*)d_in[0];
    // d_in[1] = causal mask (deterministic, unused)
    const float* wq_w  = (const float*)d_in[2];
    const float* wq_b  = (const float*)d_in[3];
    const float* wk_w  = (const float*)d_in[4];
    const float* wk_b  = (const float*)d_in[5];
    const float* wv_w  = (const float*)d_in[6];
    const float* wv_b  = (const float*)d_in[7];
    const float* wo_w  = (const float*)d_in[8];
    const float* wo_b  = (const float*)d_in[9];
    const float* fc1_w = (const float*)d_in[10];
    const float* fc1_b = (const float*)d_in[11];
    const float* fc2_w = (const float*)d_in[12];
    const float* fc2_b = (const float*)d_in[13];
    const float* ln1_g = (const float*)d_in[14];
    const float* ln1_b = (const float*)d_in[15];
    const float* ln2_g = (const float*)d_in[16];
    const float* ln2_b = (const float*)d_in[17];
    float* out = (float*)d_out;

    char* ws = (char*)d_ws;
    const size_t M1 = 1048576;
    const size_t MB = 1048576;
    u16* Wc    = (u16*)ws;
    u16* wqc   = Wc;                       // [3072][1024] fused qkv rows
    u16* woc   = Wc + 3 * M1;
    u16* f1c   = Wc + 4 * M1;
    u16* f2c   = Wc + 8 * M1;
    u16* h     = (u16*)(ws + 24 * MB);
    u16* ctx   = h;
    u16* qkv   = (u16*)(ws + 32 * MB);
    u16* vT    = (u16*)(ws + 56 * MB);
    u16* ffh   = (u16*)(ws + 32 * MB);
    float* x1  = (float*)(ws + 64 * MB);
    float* qkvb = x1;                      // 3072 fp32, dead before x1 written
    u16* h2    = h;

    const dim3 blk(256);

    static bool s_attr_done = false;
    if (!s_attr_done) {
        hipFuncSetAttribute(reinterpret_cast<const void*>(gemm256_kernel),
                            hipFuncAttributeMaxDynamicSharedMemorySize, 131072);
        hipFuncSetAttribute(reinterpret_cast<const void*>(gemm128sq_kernel),
                            hipFuncAttributeMaxDynamicSharedMemorySize, 131072);
        s_attr_done = true;
    }

    // 0. weights fp32 -> bf16 (+ fused qkv bias)
    conv_w_kernel<<<12288, 256, 0, stream>>>(wq_w, wk_w, wv_w, wo_w, fc1_w, fc2_w,
                                             wq_b, wk_b, wv_b, qkvb, Wc);
    // 1. h = LN1(x)
    ln_kernel<<<4096, 64, 0, stream>>>(x, ln1_g, ln1_b, h);
    // 2. qkv = h @ [Wq;Wk;Wv]^T + b   (fused, N=3072) — 256^2 8-phase
    gemm256_kernel<<<dim3(16 * 12), dim3(512), 131072, stream>>>(
        h, wqc, qkvb, qkv, 4096, 3072, 1024, 0);
    // 3. vT = per-head transpose of V
    transp_v<<<dim3(32, 32), blk, 0, stream>>>(qkv, vT);
    // 4. ctx = causal_attn(q,k,vT)   (swizzled, double-buffered)
    attn_kernel<<<dim3(16, 32), blk, 0, stream>>>(qkv, vT, ctx);
    // 5. x1 = x + ctx @ Wo^T + bo    (fp32 out, 128x128 deep pipeline)
    gemm128sq_kernel<<<dim3(32, 8), blk, 131072, stream>>>(
        ctx, woc, wo_b, x, x1, 4096, 1024, 1024);
    // 6. h2 = LN2(x1)
    ln_kernel<<<4096, 64, 0, stream>>>(x1, ln2_g, ln2_b, h2);
    // 7. ffh = gelu(h2 @ fc1^T + b1) — 256^2 8-phase
    gemm256_kernel<<<dim3(16 * 16), dim3(512), 131072, stream>>>(
        h2, f1c, fc1_b, ffh, 4096, 4096, 1024, 1);
    // 8. out = x1 + ffh @ fc2^T + b2 (fp32 out, 128x128 deep pipeline)
    gemm128sq_kernel<<<dim3(32, 8), blk, 131072, stream>>>(
        ffh, f2c, fc2_b, x1, out, 4096, 1024, 4096);
}

// Round 5
// 349.354 us; speedup vs baseline: 1.0908x; 1.0908x over previous
//
#include <hip/hip_runtime.h>
#include <stdint.h>

typedef unsigned short u16;
typedef __bf16 bf16x8 __attribute__((ext_vector_type(8)));
typedef float floatx4 __attribute__((ext_vector_type(4)));

#define AS1(p) ((__attribute__((address_space(1))) void*)(void*)(p))
#define AS3(p) ((__attribute__((address_space(3))) void*)(p))

__device__ __forceinline__ u16 f2bf(float f) {
    unsigned u;
    __builtin_memcpy(&u, &f, 4);
    u += 0x7FFF + ((u >> 16) & 1);   // RNE
    return (u16)(u >> 16);
}
__device__ __forceinline__ u16 f2bf_trunc(float f) {
    unsigned u;
    __builtin_memcpy(&u, &f, 4);
    return (u16)(u >> 16);
}
__device__ __forceinline__ float exp2_fast(float x) {
    return __builtin_amdgcn_exp2f(x);    // v_exp_f32
}
__device__ __forceinline__ float gelu_f(float x) {
    return 0.5f * x * (1.0f + erff(x * 0.70710678118654752f));
}

// ---------------------------------------------------------------------------
// Convert the 6 weight matrices fp32 -> bf16 into ws (layout: wq wk wv wo f1 f2)
// ---------------------------------------------------------------------------
__global__ __launch_bounds__(256) void conv_w_kernel(
    const float* __restrict__ wq, const float* __restrict__ wk,
    const float* __restrict__ wv, const float* __restrict__ wo,
    const float* __restrict__ f1, const float* __restrict__ f2,
    const float* __restrict__ bq, const float* __restrict__ bk,
    const float* __restrict__ bv, float* __restrict__ qkvb,
    u16* __restrict__ W) {
    const size_t i4 = ((size_t)blockIdx.x * 256 + threadIdx.x) * 4;
    const size_t M1 = 1048576;
    const float* src;
    size_t off;
    if (i4 < M1)            { src = wq; off = i4; }
    else if (i4 < 2 * M1)   { src = wk; off = i4 - M1; }
    else if (i4 < 3 * M1)   { src = wv; off = i4 - 2 * M1; }
    else if (i4 < 4 * M1)   { src = wo; off = i4 - 3 * M1; }
    else if (i4 < 8 * M1)   { src = f1; off = i4 - 4 * M1; }
    else                    { src = f2; off = i4 - 8 * M1; }
    float4 d = *(const float4*)(src + off);
    ushort4 o;
    o.x = f2bf(d.x); o.y = f2bf(d.y); o.z = f2bf(d.z); o.w = f2bf(d.w);
    *(ushort4*)(W + i4) = o;
    if (blockIdx.x == 0) {
        for (int i = threadIdx.x; i < 1024; i += 256) {
            qkvb[i] = bq[i];
            qkvb[1024 + i] = bk[i];
            qkvb[2048 + i] = bv[i];
        }
    }
}

// ---------------------------------------------------------------------------
// LayerNorm: one wave per token row (D=1024 -> 16 elems/lane). fp32 in, bf16 out.
// ---------------------------------------------------------------------------
__global__ __launch_bounds__(64) void ln_kernel(const float* __restrict__ X,
                                                const float* __restrict__ G,
                                                const float* __restrict__ Bt,
                                                u16* __restrict__ Y) {
    const int row = blockIdx.x;
    const int lane = threadIdx.x;
    const float* xr = X + (size_t)row * 1024;
    float v[16];
    float s = 0.f;
#pragma unroll
    for (int i = 0; i < 16; ++i) { v[i] = xr[lane + i * 64]; s += v[i]; }
#pragma unroll
    for (int off = 1; off < 64; off <<= 1) s += __shfl_xor(s, off, 64);
    const float mu = s * (1.0f / 1024.0f);
    float ss = 0.f;
#pragma unroll
    for (int i = 0; i < 16; ++i) { float d = v[i] - mu; ss += d * d; }
#pragma unroll
    for (int off = 1; off < 64; off <<= 1) ss += __shfl_xor(ss, off, 64);
    const float rstd = rsqrtf(ss * (1.0f / 1024.0f) + 1e-5f);
    u16* yr = Y + (size_t)row * 1024;
#pragma unroll
    for (int i = 0; i < 16; ++i) {
        int c = lane + i * 64;
        yr[c] = f2bf((v[i] - mu) * rstd * G[c] + Bt[c]);
    }
}

// ---------------------------------------------------------------------------
// gemm128sq: 128x128 tile, 4 waves (2Mx2N, 64x64 each), BK=64,
// 4-buffer LDS pipeline staged 3 tiles ahead (counted vmcnt 16/8/0 tail),
// T2 XOR-swizzle (rule #21), setprio around the 32-MFMA cluster.
// fp32 out = A@Bt^T + bias + resid. Grid (M/128, N/128). 128 KiB dyn LDS.
// ---------------------------------------------------------------------------
__global__ __launch_bounds__(256, 1) void gemm128sq_kernel(
    const u16* __restrict__ A, const u16* __restrict__ Bt,
    const float* __restrict__ bias, const float* __restrict__ resid,
    float* __restrict__ C, int M, int N, int K) {
    extern __shared__ __align__(16) u16 smem[];   // 4 bufs x (A 8192 + B 8192) u16
    const int tid = threadIdx.x;
    const int wave = tid >> 6, lane = tid & 63;
    const int wm = (wave >> 1) * 64;
    const int wn = (wave & 1) * 64;
    const int lr = lane & 15, lk8 = (lane >> 4) * 8;
    const int r0 = (lane >> 4) * 4;
    const int m0 = blockIdx.x * 128, n0 = blockIdx.y * 128;
    const int NT = K >> 6;                        // 16 or 64
    const u16* const Ab = A + (size_t)m0 * K;
    const u16* const Bb = Bt + (size_t)n0 * K;

    const int srow = tid >> 3;                    // 0..31
    const int scol = 8 * ((tid & 7) ^ (srow & 7));
    const int sdst = tid * 8;                     // u16 offset within 2048-u16 chunk
    const int swz = (lr & 7) << 3;
    const int c0 = lk8 ^ swz;
    const int c1 = (32 + lk8) ^ swz;

    floatx4 acc[4][4];
#pragma unroll
    for (int i = 0; i < 4; ++i)
#pragma unroll
        for (int j = 0; j < 4; ++j) acc[i][j] = floatx4{0.f, 0.f, 0.f, 0.f};
    bf16x8 aF[4][2], bF[4][2];

#define STG(Tt)                                                                \
    {                                                                          \
        u16* const buf = smem + ((Tt) & 3) * 16384;                            \
        _Pragma("unroll")                                                      \
        for (int l = 0; l < 4; ++l) {                                          \
            const u16* srcA = Ab + (size_t)(l * 32 + srow) * K +               \
                              (size_t)(Tt) * 64 + scol;                        \
            __builtin_amdgcn_global_load_lds(                                  \
                AS1(srcA), AS3(buf + l * 2048 + sdst), 16, 0, 0);              \
        }                                                                      \
        _Pragma("unroll")                                                      \
        for (int l = 0; l < 4; ++l) {                                          \
            const u16* srcB = Bb + (size_t)(l * 32 + srow) * K +               \
                              (size_t)(Tt) * 64 + scol;                        \
            __builtin_amdgcn_global_load_lds(                                  \
                AS1(srcB), AS3(buf + 8192 + l * 2048 + sdst), 16, 0, 0);       \
        }                                                                      \
    }

    STG(0); STG(1); STG(2);
    for (int T = 0; T < NT; ++T) {
        const int rem = NT - 1 - T;
        if (rem >= 2)      asm volatile("s_waitcnt vmcnt(16)" ::: "memory");
        else if (rem == 1) asm volatile("s_waitcnt vmcnt(8)" ::: "memory");
        else               asm volatile("s_waitcnt vmcnt(0)" ::: "memory");
        asm volatile("s_barrier" ::: "memory");
        if (T + 3 < NT) STG(T + 3);
        const u16* const bufA = smem + (T & 3) * 16384;
        const u16* const bufB = bufA + 8192;
#pragma unroll
        for (int i = 0; i < 4; ++i) {
            aF[i][0] = *(const bf16x8*)&bufA[(wm + i * 16 + lr) * 64 + c0];
            aF[i][1] = *(const bf16x8*)&bufA[(wm + i * 16 + lr) * 64 + c1];
        }
#pragma unroll
        for (int j = 0; j < 4; ++j) {
            bF[j][0] = *(const bf16x8*)&bufB[(wn + j * 16 + lr) * 64 + c0];
            bF[j][1] = *(const bf16x8*)&bufB[(wn + j * 16 + lr) * 64 + c1];
        }
        asm volatile("s_waitcnt lgkmcnt(0)" ::: "memory");
        __builtin_amdgcn_sched_barrier(0);
        __builtin_amdgcn_s_setprio(1);
#pragma unroll
        for (int i = 0; i < 4; ++i)
#pragma unroll
            for (int j = 0; j < 4; ++j)
#pragma unroll
                for (int kk = 0; kk < 2; ++kk)
                    acc[i][j] = __builtin_amdgcn_mfma_f32_16x16x32_bf16(
                        aF[i][kk], bF[j][kk], acc[i][j], 0, 0, 0);
        __builtin_amdgcn_s_setprio(0);
    }
#undef STG

    // epilogue: fp32 out = acc + bias + resid
#pragma unroll
    for (int i = 0; i < 4; ++i)
#pragma unroll
        for (int j = 0; j < 4; ++j) {
            const int col = n0 + wn + j * 16 + lr;
            const float bv = bias[col];
#pragma unroll
            for (int r = 0; r < 4; ++r) {
                const int row = m0 + wm + i * 16 + r0 + r;
                C[(size_t)row * N + col] =
                    acc[i][j][r] + bv + resid[(size_t)row * N + col];
            }
        }
}

// ---------------------------------------------------------------------------
// gemm256 v2: 256x256 tile, BK=64, 8 waves (2Mx4N), 4-phase/K-tile pipeline.
// REGISTER-DIETED: single aF[4][2] (32 VGPR) overwritten at ph3 — keeps total
// regs ~220, well under the 256/wave cap of __launch_bounds__(512,2) (the
// round-4 regression was a regalloc spill cliff at exactly 256).
// Finer read interleave (12/4/8/0 ds_reads per phase + 1 stage per phase).
// Schedule per GROUP(P, T) (tile T in bufs parity P):
//   ph1: read aF<-mq0(8), bF01(4); stage B0(T+1)->P^1; BAR; lgkm0; Q(0,0)
//   ph2: read bF23(4);             stage B1(T+1)->P^1; BAR; lgkm0; Q(0,1)
//   ph3: read aF<-mq1(8);          lgkm0; Q(1,0); BAR  [all A reads retired]
//   ph4: stage A0,A1(T+2)->P;      Q(1,1); vmcnt(4|0); BAR
// vmcnt bookkeeping (steady state): enter group with A(T+1)=4 outstanding;
// +2 +2 +4 issued -> 12; vmcnt(4) retires A(T+1)+B(T+1), keeps A(T+2). ✓
// ---------------------------------------------------------------------------
__global__ __launch_bounds__(512, 2) void gemm256_kernel(
    const u16* __restrict__ A, const u16* __restrict__ Bt,
    const float* __restrict__ bias, u16* __restrict__ C,
    int M, int N, int K, int act) {
    extern __shared__ __align__(16) u16 smem[];
    u16* const lA = smem;          // [2][256*64] = 64 KiB
    u16* const lB = smem + 32768;  // [2][256*64] = 64 KiB
    const int tid = threadIdx.x;
    const int wave = tid >> 6, lane = tid & 63;
    const int wm = (wave >> 2) * 128;        // wave M-origin (0/128)
    const int wn = (wave & 3) * 64;          // wave N-origin (0/64/128/192)
    const int lr = lane & 15, lk8 = (lane >> 4) * 8;
    const int r0 = (lane >> 4) * 4;

    const int gM = M >> 8;
    int bid = blockIdx.x;
    { const int nwg = gridDim.x;
      const int q = nwg >> 3, r = nwg & 7, xcd = bid & 7, lid = bid >> 3;
      bid = (xcd < r ? xcd * (q + 1) : r * (q + 1) + (xcd - r) * q) + lid; }
    const int m0 = (bid % gM) << 8;
    const int n0 = (bid / gM) << 8;

    const int NT = K >> 6;                   // 16 here (even)
    const u16* const Ab = A + (size_t)m0 * K;
    const u16* const Bb = Bt + (size_t)n0 * K;

    const int srow = tid >> 3;                         // 0..63
    const int scol = 8 * ((tid & 7) ^ (srow & 7));     // element col, inv-swizzled
    const int sdst = tid * 8;                          // u16 offset (lane*16 B)
    const int swz = (lr & 7) << 3;
    const int c0 = lk8 ^ swz;                          // kk=0 frag col
    const int c1 = (32 + lk8) ^ swz;                   // kk=1 frag col

    floatx4 acc[8][4];
#pragma unroll
    for (int i = 0; i < 8; ++i)
#pragma unroll
        for (int j = 0; j < 4; ++j) acc[i][j] = floatx4{0.f, 0.f, 0.f, 0.f};
    bf16x8 aF[4][2];      // CURRENT mq half only (overwritten at ph3)
    bf16x8 bF[4][2];      // [nf][kk]

#define STAGE_HT(ldsbuf, gbase, h, Tt)                                         \
    {                                                                          \
        _Pragma("unroll")                                                      \
        for (int l = 0; l < 2; ++l) {                                          \
            const u16* src = (gbase) + (size_t)((h) * 128 + l * 64 + srow) * K \
                             + (size_t)(Tt) * 64 + scol;                       \
            __builtin_amdgcn_global_load_lds(                                  \
                AS1(src), AS3((ldsbuf) + (h) * 8192 + l * 4096 + sdst), 16, 0, 0); \
        }                                                                      \
    }
#define PH_BAR() asm volatile("s_barrier" ::: "memory")
#define LGKM0()                                                                \
    do { asm volatile("s_waitcnt lgkmcnt(0)" ::: "memory");                    \
         __builtin_amdgcn_sched_barrier(0); } while (0)
#define RD_A(lAp, mq)                                                          \
    _Pragma("unroll")                                                          \
    for (int i = 0; i < 4; ++i) {                                              \
        aF[i][0] = *(const bf16x8*)&(lAp)[(wm + (mq) * 64 + i * 16 + lr) * 64 + c0]; \
        aF[i][1] = *(const bf16x8*)&(lAp)[(wm + (mq) * 64 + i * 16 + lr) * 64 + c1]; \
    }
#define RD_B2(lBp, nf0)                                                        \
    _Pragma("unroll")                                                          \
    for (int j = 0; j < 2; ++j) {                                              \
        bF[(nf0) + j][0] = *(const bf16x8*)&(lBp)[(wn + ((nf0) + j) * 16 + lr) * 64 + c0]; \
        bF[(nf0) + j][1] = *(const bf16x8*)&(lBp)[(wn + ((nf0) + j) * 16 + lr) * 64 + c1]; \
    }
#define MFMA_Q(mq, nq)                                                         \
    __builtin_amdgcn_s_setprio(1);                                             \
    _Pragma("unroll")                                                          \
    for (int i = 0; i < 4; ++i)                                                \
        _Pragma("unroll")                                                      \
        for (int j = 0; j < 2; ++j)                                            \
            _Pragma("unroll")                                                  \
            for (int kk = 0; kk < 2; ++kk)                                     \
                acc[(mq) * 4 + i][(nq) * 2 + j] =                              \
                    __builtin_amdgcn_mfma_f32_16x16x32_bf16(                   \
                        aF[i][kk], bF[(nq) * 2 + j][kk],                       \
                        acc[(mq) * 4 + i][(nq) * 2 + j], 0, 0, 0);             \
    __builtin_amdgcn_s_setprio(0);

#define GROUP(P, T)                                                            \
    {                                                                          \
        u16* const lAp = lA + (P) * 16384;                                     \
        u16* const lBp = lB + (P) * 16384;                                     \
        u16* const lBn = lB + ((P) ^ 1) * 16384;                               \
        /* ph1 */                                                              \
        RD_A(lAp, 0);                                                          \
        RD_B2(lBp, 0);                                                         \
        if ((T) + 1 < NT) STAGE_HT(lBn, Bb, 0, (T) + 1);                       \
        PH_BAR(); LGKM0();                                                     \
        MFMA_Q(0, 0);                                                          \
        /* ph2 */                                                              \
        RD_B2(lBp, 2);                                                         \
        if ((T) + 1 < NT) STAGE_HT(lBn, Bb, 1, (T) + 1);                       \
        PH_BAR(); LGKM0();                                                     \
        MFMA_Q(0, 1);                                                          \
        /* ph3: overwrite aF with mq1 half */                                  \
        RD_A(lAp, 1);                                                          \
        LGKM0();                                                               \
        MFMA_Q(1, 0);                                                          \
        PH_BAR();  /* all waves' A reads of buf P retired */                   \
        /* ph4 */                                                              \
        if ((T) + 2 < NT) {                                                    \
            STAGE_HT(lAp, Ab, 0, (T) + 2);                                     \
            STAGE_HT(lAp, Ab, 1, (T) + 2);                                     \
        }                                                                      \
        MFMA_Q(1, 1);                                                          \
        if ((T) + 2 < NT) asm volatile("s_waitcnt vmcnt(4)" ::: "memory");     \
        else              asm volatile("s_waitcnt vmcnt(0)" ::: "memory");     \
        PH_BAR();                                                              \
    }

    // prologue: T0 fully + T1 A-halves issued (12 loads); wait oldest 8 (= T0)
    STAGE_HT(lA, Ab, 0, 0);
    STAGE_HT(lA, Ab, 1, 0);
    STAGE_HT(lB, Bb, 0, 0);
    STAGE_HT(lB, Bb, 1, 0);
    if (NT > 1) {
        STAGE_HT(lA + 16384, Ab, 0, 1);
        STAGE_HT(lA + 16384, Ab, 1, 1);
    }
    asm volatile("s_waitcnt vmcnt(4)" ::: "memory");
    PH_BAR();

    for (int T = 0; T < NT; T += 2) {
        GROUP(0, T);
        GROUP(1, T + 1);
    }
#undef GROUP
#undef MFMA_Q
#undef RD_B2
#undef RD_A
#undef LGKM0
#undef PH_BAR
#undef STAGE_HT

    // epilogue: bias (+gelu) -> bf16
#pragma unroll
    for (int mq = 0; mq < 2; ++mq)
#pragma unroll
        for (int i = 0; i < 4; ++i)
#pragma unroll
            for (int nf = 0; nf < 4; ++nf) {
                const int col = n0 + wn + nf * 16 + lr;
                const float bv = bias[col];
                floatx4 v = acc[mq * 4 + i][nf];
#pragma unroll
                for (int r = 0; r < 4; ++r) {
                    const int row = m0 + wm + mq * 64 + i * 16 + r0 + r;
                    float x = v[r] + bv;
                    if (act) x = gelu_f(x);
                    C[(size_t)row * N + col] = f2bf(x);
                }
            }
}

// ---------------------------------------------------------------------------
// Transpose the V columns of qkv [4096][3072] into vT [32*64][2048]
// ---------------------------------------------------------------------------
__global__ __launch_bounds__(256) void transp_v(const u16* __restrict__ qkv,
                                                u16* __restrict__ vT) {
    __shared__ u16 lT[64 * 64];
    const int bh = blockIdx.x, tt = blockIdx.y;
    const int b = bh >> 4, h = bh & 15;
    const int t0 = tt * 64;
    const int tid = threadIdx.x;
    const int srow = tid >> 3, scol = (tid & 7) * 8;
#pragma unroll
    for (int rr = 0; rr < 2; ++rr) {
        const int row = srow + rr * 32;  // t-local
        uint4 d4 = *(const uint4*)(qkv + (size_t)(b * 2048 + t0 + row) * 3072 +
                                   2048 + h * 64 + scol);
        const u16* e = (const u16*)&d4;
#pragma unroll
        for (int t = 0; t < 8; ++t) lT[(scol + t) * 64 + row] = e[t];
    }
    __syncthreads();
#pragma unroll
    for (int rr = 0; rr < 2; ++rr) {
        const int row = srow + rr * 32;  // d index
        uint4 d4 = *(const uint4*)&lT[row * 64 + scol];
        *(uint4*)(vT + (size_t)(bh * 64 + row) * 2048 + t0 + scol) = d4;
    }
}

// ---------------------------------------------------------------------------
// Causal flash attention v6: merged pair + max-free softmax + T2 XOR-swizzle
// on all K/V/P LDS paths + double-buffered K/V with counted vmcnt(4) +
// setprio around MFMA clusters.
// ---------------------------------------------------------------------------
__global__ __launch_bounds__(256) void attn_kernel(const u16* __restrict__ qkv,
                                                   const u16* __restrict__ vT,
                                                   u16* __restrict__ O) {
    __shared__ __align__(16) u16 lK[2][64 * 64];     // [buf][key][dh]  16 KiB
    __shared__ __align__(16) u16 lV[2][64 * 64];     // [buf][dh][key]  16 KiB
    __shared__ __align__(16) u16 lP[4][16 * 64];     // per-wave P       8 KiB
    const int tid = threadIdx.x;
    const int wave = tid >> 6, lane = tid & 63;
    const int lr = lane & 15, khi = lane >> 4, lk8 = khi * 8;
    const int p = blockIdx.x;                        // 0..15; qa=31-p first
    const int bh = blockIdx.y;
    const int b = bh >> 4, hh = bh & 15;
    const int rb = b * 2048;
    const size_t vbase = (size_t)(bh * 64) * 2048;
    const int r0 = khi * 4;
    const int qa = 31 - p, qb = p;
    const int qa0 = qa * 64, qb0 = qb * 64;
    const float C = 0.125f * 1.44269504088896f;      // scale * log2(e)

    // staging: linear LDS dest (rr*2048 + tid*8 u16), inverse-swizzled global col
    const int srow = tid >> 3;                       // 0..31
    const int scol = 8 * ((tid & 7) ^ (srow & 7));   // swizzled col within 64
    const int sdst = tid * 8;
    // read-side swizzle: col c at LDS row -> c ^ ((row&7)<<3); row&7 == lr&7
    const int swz = (lr & 7) << 3;
    const int cc0 = lk8 ^ swz;
    const int cc1 = (32 + lk8) ^ swz;

    // Q A-fragments for both tiles (direct from global; no LDS)
    bf16x8 aqA0, aqA1, aqB0, aqB1;
    {
        const size_t qoffA = (size_t)(rb + qa0 + wave * 16 + lr) * 3072 + hh * 64;
        aqA0 = *(const bf16x8*)(qkv + qoffA + lk8);
        aqA1 = *(const bf16x8*)(qkv + qoffA + 32 + lk8);
        const size_t qoffB = (size_t)(rb + qb0 + wave * 16 + lr) * 3072 + hh * 64;
        aqB0 = *(const bf16x8*)(qkv + qoffB + lk8);
        aqB1 = *(const bf16x8*)(qkv + qoffB + 32 + lk8);
    }

    floatx4 oA[4], oB[4];
    float lA_[4], lB_[4];                            // per-lane partial sums
#pragma unroll
    for (int r = 0; r < 4; ++r) {
        oA[r] = floatx4{0.f, 0.f, 0.f, 0.f};
        oB[r] = floatx4{0.f, 0.f, 0.f, 0.f};
        lA_[r] = 0.f; lB_[r] = 0.f;
    }

#define ASTAGE(Pb, kt_)                                                        \
    {                                                                          \
        const int k0_ = (kt_) * 64;                                            \
        _Pragma("unroll")                                                      \
        for (int rr = 0; rr < 2; ++rr) {                                       \
            const int row = srow + rr * 32;                                    \
            __builtin_amdgcn_global_load_lds(                                  \
                AS1(qkv + (size_t)(rb + k0_ + row) * 3072 + 1024 + hh * 64 + scol), \
                AS3(lK[Pb] + rr * 2048 + sdst), 16, 0, 0);                     \
            __builtin_amdgcn_global_load_lds(                                  \
                AS1(vT + vbase + (size_t)row * 2048 + k0_ + scol),             \
                AS3(lV[Pb] + rr * 2048 + sdst), 16, 0, 0);                     \
        }                                                                      \
    }

    // One QK->exp->PV round for one tile against the staged k-tile (buf Pb).
#define TILE_ROUND(Pb, aq0_, aq1_, oo_, ll_, q0_, diag_, k0_)                   \
    {                                                                           \
        float s[4][4];                                                          \
        __builtin_amdgcn_s_setprio(1);                                          \
        _Pragma("unroll")                                                       \
        for (int j = 0; j < 4; ++j) {                                           \
            bf16x8 bk0 = *(const bf16x8*)&lK[Pb][(j * 16 + lr) * 64 + cc0];     \
            bf16x8 bk1 = *(const bf16x8*)&lK[Pb][(j * 16 + lr) * 64 + cc1];     \
            floatx4 t = floatx4{0.f, 0.f, 0.f, 0.f};                            \
            t = __builtin_amdgcn_mfma_f32_16x16x32_bf16(aq0_, bk0, t, 0, 0, 0); \
            t = __builtin_amdgcn_mfma_f32_16x16x32_bf16(aq1_, bk1, t, 0, 0, 0); \
            _Pragma("unroll")                                                   \
            for (int r = 0; r < 4; ++r) s[j][r] = t[r];                         \
        }                                                                       \
        __builtin_amdgcn_s_setprio(0);                                          \
        if (diag_) {                                                            \
            _Pragma("unroll")                                                   \
            for (int j = 0; j < 4; ++j)                                         \
                _Pragma("unroll")                                               \
                for (int r = 0; r < 4; ++r)                                     \
                    if ((k0_) + j * 16 + lr > (q0_) + wave * 16 + r0 + r)       \
                        s[j][r] = -1e30f;                                       \
        }                                                                       \
        _Pragma("unroll")                                                       \
        for (int j = 0; j < 4; ++j)                                             \
            _Pragma("unroll")                                                   \
            for (int r = 0; r < 4; ++r) {                                       \
                float pv = exp2_fast(s[j][r] * C);                              \
                ll_[r] += pv;                                                   \
                lP[wave][(r0 + r) * 64 +                                        \
                         ((j * 16 + lr) ^ (((r0 + r) & 7) << 3))] =             \
                    f2bf_trunc(pv);                                             \
            }                                                                   \
        bf16x8 ap0 = *(const bf16x8*)&lP[wave][lr * 64 + cc0];                  \
        bf16x8 ap1 = *(const bf16x8*)&lP[wave][lr * 64 + cc1];                  \
        __builtin_amdgcn_s_setprio(1);                                          \
        _Pragma("unroll")                                                       \
        for (int jd = 0; jd < 4; ++jd) {                                        \
            bf16x8 bv0 = *(const bf16x8*)&lV[Pb][(jd * 16 + lr) * 64 + cc0];    \
            bf16x8 bv1 = *(const bf16x8*)&lV[Pb][(jd * 16 + lr) * 64 + cc1];    \
            oo_[jd] = __builtin_amdgcn_mfma_f32_16x16x32_bf16(ap0, bv0, oo_[jd], 0, 0, 0); \
            oo_[jd] = __builtin_amdgcn_mfma_f32_16x16x32_bf16(ap1, bv1, oo_[jd], 0, 0, 0); \
        }                                                                       \
        __builtin_amdgcn_s_setprio(0);                                          \
    }

    ASTAGE(0, 0);
    for (int kt = 0; kt <= qa; ++kt) {
        const int P = kt & 1;
        const int k0 = kt * 64;
        if (kt < qa) {
            ASTAGE(P ^ 1, kt + 1);
            asm volatile("s_waitcnt vmcnt(4)" ::: "memory");
        } else {
            asm volatile("s_waitcnt vmcnt(0)" ::: "memory");
        }
        asm volatile("s_barrier" ::: "memory");

        TILE_ROUND(P, aqA0, aqA1, oA, lA_, qa0, kt == qa, k0);
        if (kt <= qb)
            TILE_ROUND(P, aqB0, aqB1, oB, lB_, qb0, kt == qb, k0);

        asm volatile("s_barrier" ::: "memory");  // retire buf-P reads before restage
    }
#undef TILE_ROUND
#undef ASTAGE

    // one-time denominator reduce over the 16 lanes sharing khi (lr bits)
#pragma unroll
    for (int off = 1; off < 16; off <<= 1)
#pragma unroll
        for (int r = 0; r < 4; ++r) {
            lA_[r] += __shfl_xor(lA_[r], off, 64);
            lB_[r] += __shfl_xor(lB_[r], off, 64);
        }

    // normalize + store ctx for both tiles (lane's rows are khi*4+r)
#pragma unroll
    for (int r = 0; r < 4; ++r) {
        const float invA = 1.0f / lA_[r];
        const float invB = 1.0f / lB_[r];
#pragma unroll
        for (int jd = 0; jd < 4; ++jd) {
            const size_t offA = (size_t)(rb + qa0 + wave * 16 + r0 + r) * 1024 +
                                hh * 64 + jd * 16 + lr;
            O[offA] = f2bf(oA[jd][r] * invA);
            const size_t offB = (size_t)(rb + qb0 + wave * 16 + r0 + r) * 1024 +
                                hh * 64 + jd * 16 + lr;
            O[offB] = f2bf(oB[jd][r] * invB);
        }
    }
}

// ---------------------------------------------------------------------------
extern "C" void kernel_launch(void* const* d_in, const int* in_sizes, int n_in,
                              void* d_out, int out_size, void* d_ws, size_t ws_size,
                              hipStream_t stream) {
    const float* x     = (const float*)d_in[0];
    // d_in[1] = causal mask (deterministic, unused)
    const float* wq_w  = (const float*)d_in[2];
    const float* wq_b  = (const float*)d_in[3];
    const float* wk_w  = (const float*)d_in[4];
    const float* wk_b  = (const float*)d_in[5];
    const float* wv_w  = (const float*)d_in[6];
    const float* wv_b  = (const float*)d_in[7];
    const float* wo_w  = (const float*)d_in[8];
    const float* wo_b  = (const float*)d_in[9];
    const float* fc1_w = (const float*)d_in[10];
    const float* fc1_b = (const float*)d_in[11];
    const float* fc2_w = (const float*)d_in[12];
    const float* fc2_b = (const float*)d_in[13];
    const float* ln1_g = (const float*)d_in[14];
    const float* ln1_b = (const float*)d_in[15];
    const float* ln2_g = (const float*)d_in[16];
    const float* ln2_b = (const float*)d_in[17];
    float* out = (float*)d_out;

    char* ws = (char*)d_ws;
    const size_t M1 = 1048576;
    const size_t MB = 1048576;
    u16* Wc    = (u16*)ws;
    u16* wqc   = Wc;                       // [3072][1024] fused qkv rows
    u16* woc   = Wc + 3 * M1;
    u16* f1c   = Wc + 4 * M1;
    u16* f2c   = Wc + 8 * M1;
    u16* h     = (u16*)(ws + 24 * MB);
    u16* ctx   = h;
    u16* qkv   = (u16*)(ws + 32 * MB);
    u16* vT    = (u16*)(ws + 56 * MB);
    u16* ffh   = (u16*)(ws + 32 * MB);
    float* x1  = (float*)(ws + 64 * MB);
    float* qkvb = x1;                      // 3072 fp32, dead before x1 written
    u16* h2    = h;

    const dim3 blk(256);

    static bool s_attr_done = false;
    if (!s_attr_done) {
        hipFuncSetAttribute(reinterpret_cast<const void*>(gemm256_kernel),
                            hipFuncAttributeMaxDynamicSharedMemorySize, 131072);
        hipFuncSetAttribute(reinterpret_cast<const void*>(gemm128sq_kernel),
                            hipFuncAttributeMaxDynamicSharedMemorySize, 131072);
        s_attr_done = true;
    }

    // 0. weights fp32 -> bf16 (+ fused qkv bias)
    conv_w_kernel<<<12288, 256, 0, stream>>>(wq_w, wk_w, wv_w, wo_w, fc1_w, fc2_w,
                                             wq_b, wk_b, wv_b, qkvb, Wc);
    // 1. h = LN1(x)
    ln_kernel<<<4096, 64, 0, stream>>>(x, ln1_g, ln1_b, h);
    // 2. qkv = h @ [Wq;Wk;Wv]^T + b   (fused, N=3072) — 256^2 4-phase v2
    gemm256_kernel<<<dim3(16 * 12), dim3(512), 131072, stream>>>(
        h, wqc, qkvb, qkv, 4096, 3072, 1024, 0);
    // 3. vT = per-head transpose of V
    transp_v<<<dim3(32, 32), blk, 0, stream>>>(qkv, vT);
    // 4. ctx = causal_attn(q,k,vT)   (swizzled, double-buffered)
    attn_kernel<<<dim3(16, 32), blk, 0, stream>>>(qkv, vT, ctx);
    // 5. x1 = x + ctx @ Wo^T + bo    (fp32 out, 128x128 deep pipeline)
    gemm128sq_kernel<<<dim3(32, 8), blk, 131072, stream>>>(
        ctx, woc, wo_b, x, x1, 4096, 1024, 1024);
    // 6. h2 = LN2(x1)
    ln_kernel<<<4096, 64, 0, stream>>>(x1, ln2_g, ln2_b, h2);
    // 7. ffh = gelu(h2 @ fc1^T + b1) — 256^2 4-phase v2
    gemm256_kernel<<<dim3(16 * 16), dim3(512), 131072, stream>>>(
        h2, f1c, fc1_b, ffh, 4096, 4096, 1024, 1);
    // 8. out = x1 + ffh @ fc2^T + b2 (fp32 out, 128x128 deep pipeline)
    gemm128sq_kernel<<<dim3(32, 8), blk, 131072, stream>>>(
        ffh, f2c, fc2_b, x1, out, 4096, 1024, 4096);
}